// Round 1
// baseline (2119.429 us; speedup 1.0000x reference)
//
#include <hip/hip_runtime.h>
#include <cstdint>

typedef __bf16 bf16_t;
typedef __bf16 bf16x2 __attribute__((ext_vector_type(2)));
typedef __bf16 bf16x4 __attribute__((ext_vector_type(4)));
typedef __bf16 bf16x8 __attribute__((ext_vector_type(8)));
typedef float f32x4 __attribute__((ext_vector_type(4)));

#define DEVI static __device__ __forceinline__

// async global->LDS, 16B per lane; LDS base must be wave-uniform (dest = base + lane*16)
DEVI void g2l16(const void* g, void* l) {
  __builtin_amdgcn_global_load_lds((__attribute__((address_space(1))) void*)g,
                                   (__attribute__((address_space(3))) void*)l,
                                   16, 0, 0);
}

// ---------------- f32 -> bf16 convert ----------------
__global__ void k_f2b(const float* __restrict__ in, bf16_t* __restrict__ out, long n4) {
  long stride = (long)gridDim.x * blockDim.x;
  for (long i = (long)blockIdx.x * blockDim.x + threadIdx.x; i < n4; i += stride) {
    float4 v = ((const float4*)in)[i];
    bf16x4 o = {(bf16_t)v.x, (bf16_t)v.y, (bf16_t)v.z, (bf16_t)v.w};
    ((bf16x4*)out)[i] = o;
  }
}

// ---------------- embedding ----------------
__global__ void k_embed(const int* __restrict__ ids, const float* __restrict__ tok,
                        const float* __restrict__ pos, float* __restrict__ x,
                        bf16_t* __restrict__ xb) {
  int r = blockIdx.x;        // 0..4095 = b*2048+t
  int t = r & 2047;
  long id = ids[r];
  int d = threadIdx.x * 2;
  float2 a = *(const float2*)(tok + id * 512 + d);
  float2 p = *(const float2*)(pos + (long)t * 512 + d);
  float o0 = a.x + p.x, o1 = a.y + p.y;
  *(float2*)(x + (long)r * 512 + d) = make_float2(o0, o1);
  bf16x2 ob = {(bf16_t)o0, (bf16_t)o1};
  *(bf16x2*)(xb + (long)r * 512 + d) = ob;
}

// ---------------- batched GEMM: C[M,N] = (A[M,K] @ B[N,K]^T + bias) * alpha ----------------
// 128x128 tile, BK=32, 4 waves (2x2), each wave 4x4 frags of 16x16x32 bf16 MFMA.
template <typename CT, bool BIAS>
__global__ __launch_bounds__(256, 2) void k_gemm_bt(
    const bf16_t* __restrict__ A, long long sAb, int lda,
    const bf16_t* __restrict__ B, long long sBb, int ldb,
    CT* __restrict__ C, long long sCb, int ldc,
    const float* __restrict__ bias, int N, int K, float alpha) {
  __shared__ bf16_t As[4096];  // [128][32]
  __shared__ bf16_t Bs[4096];  // [128][32]
  const int tid = threadIdx.x;
  const int lane = tid & 63;
  const int w = tid >> 6;
  const int wm = w >> 1, wn = w & 1;
  const long long m0 = (long long)blockIdx.y * 128;
  const int n0 = blockIdx.x * 128;
  A += (long long)blockIdx.z * sAb;
  B += (long long)blockIdx.z * sBb;
  C += (long long)blockIdx.z * sCb;

  f32x4 acc[4][4];
#pragma unroll
  for (int m = 0; m < 4; ++m)
#pragma unroll
    for (int n = 0; n < 4; ++n) acc[m][n] = (f32x4){0.f, 0.f, 0.f, 0.f};

  const int srow = tid >> 2;         // staging row within 64-row half
  const int scol = (tid & 3) * 8;    // staging col (8 bf16 = 16B)
  const int fr = lane & 15;          // fragment row (A) / col (B)
  const int kg = (lane >> 4) * 8;    // fragment k-offset

  for (int k0 = 0; k0 < K; k0 += 32) {
#pragma unroll
    for (int p = 0; p < 2; ++p) {
      const bf16_t* ga = A + (m0 + p * 64 + srow) * (long long)lda + (k0 + scol);
      g2l16(ga, As + p * 2048 + w * 512);
      int rb = n0 + p * 64 + srow;
      if (rb >= N) rb = N - 1;  // clamp (garbage cols masked at store)
      const bf16_t* gb = B + (long long)rb * ldb + (k0 + scol);
      g2l16(gb, Bs + p * 2048 + w * 512);
    }
    __syncthreads();
    bf16x8 fa[4], fb[4];
#pragma unroll
    for (int m = 0; m < 4; ++m)
      fa[m] = *(const bf16x8*)(As + (wm * 64 + m * 16 + fr) * 32 + kg);
#pragma unroll
    for (int n = 0; n < 4; ++n)
      fb[n] = *(const bf16x8*)(Bs + (wn * 64 + n * 16 + fr) * 32 + kg);
#pragma unroll
    for (int m = 0; m < 4; ++m)
#pragma unroll
      for (int n = 0; n < 4; ++n)
        acc[m][n] = __builtin_amdgcn_mfma_f32_16x16x32_bf16(fa[m], fb[n], acc[m][n], 0, 0, 0);
    __syncthreads();
  }

  const int r0 = (lane >> 4) * 4;  // C/D: col=lane&15, row=(lane>>4)*4+reg
#pragma unroll
  for (int n = 0; n < 4; ++n) {
    const int col = n0 + wn * 64 + n * 16 + fr;
    if (col >= N) continue;
    const float bv = BIAS ? bias[col] : 0.0f;
#pragma unroll
    for (int m = 0; m < 4; ++m) {
      const long long row = m0 + wm * 64 + m * 16 + r0;
#pragma unroll
      for (int r = 0; r < 4; ++r) {
        float v = (acc[m][n][r] + bv) * alpha;
        C[(row + r) * (long long)ldc + col] = (CT)v;
      }
    }
  }
}

// ---------------- row softmax over 2048 bf16, in place ----------------
__global__ void k_softmax(bf16_t* __restrict__ att) {
  __shared__ float red[4];
  bf16_t* p = att + (long long)blockIdx.x * 2048;
  const int tid = threadIdx.x;
  const int lane = tid & 63, w = tid >> 6;
  bf16x8 v = *(const bf16x8*)(p + tid * 8);
  float f[8];
  float mx = -1e30f;
#pragma unroll
  for (int j = 0; j < 8; ++j) { f[j] = (float)v[j]; mx = fmaxf(mx, f[j]); }
#pragma unroll
  for (int o = 32; o > 0; o >>= 1) mx = fmaxf(mx, __shfl_xor(mx, o));
  if (lane == 0) red[w] = mx;
  __syncthreads();
  mx = fmaxf(fmaxf(red[0], red[1]), fmaxf(red[2], red[3]));
  __syncthreads();
  float s = 0.f;
#pragma unroll
  for (int j = 0; j < 8; ++j) { f[j] = __expf(f[j] - mx); s += f[j]; }
#pragma unroll
  for (int o = 32; o > 0; o >>= 1) s += __shfl_xor(s, o);
  if (lane == 0) red[w] = s;
  __syncthreads();
  s = red[0] + red[1] + red[2] + red[3];
  const float inv = 1.0f / s;
  bf16x8 ov;
#pragma unroll
  for (int j = 0; j < 8; ++j) ov[j] = (bf16_t)(f[j] * inv);
  *(bf16x8*)(p + tid * 8) = ov;
}

// ---------------- qkv split: q*0.125 -> [bh,t,hd]; k -> [bh,t,hd]; v -> [bh,hd,t] ----------------
__global__ void k_qkv_split(const float* __restrict__ qkv, bf16_t* __restrict__ qh,
                            bf16_t* __restrict__ kh, bf16_t* __restrict__ vt) {
  long i = (long)blockIdx.x * 256 + threadIdx.x;  // over 4096*512
  int r = (int)(i >> 9);
  int d = (int)(i & 511);
  int b = r >> 11, t = r & 2047;
  int h = d >> 6, hd = d & 63;
  const float* src = qkv + (long)r * 1536;
  long bh = (long)b * 8 + h;
  qh[(bh * 2048 + t) * 64 + hd] = (bf16_t)(src[d] * 0.125f);
  kh[(bh * 2048 + t) * 64 + hd] = (bf16_t)(src[512 + d]);
  vt[(bh * 64 + hd) * 2048 + t] = (bf16_t)(src[1024 + d]);
}

// ---------------- LN(xin + delta) * s + b -> xout (f32) + xbf (bf16), D=512 ----------------
__global__ void k_ln(const float* __restrict__ xin, const float* __restrict__ delta,
                     const float* __restrict__ s, const float* __restrict__ b,
                     float* __restrict__ xout, bf16_t* __restrict__ xbf) {
  __shared__ float red[8];
  const int r = blockIdx.x;
  const int tid = threadIdx.x;
  const int d = tid * 2;
  const int lane = tid & 63, w = tid >> 6;
  float2 xi = *(const float2*)(xin + (long)r * 512 + d);
  float2 de = *(const float2*)(delta + (long)r * 512 + d);
  float y0 = xi.x + de.x, y1 = xi.y + de.y;
  float sum = y0 + y1, ss = y0 * y0 + y1 * y1;
#pragma unroll
  for (int o = 32; o > 0; o >>= 1) { sum += __shfl_xor(sum, o); ss += __shfl_xor(ss, o); }
  if (lane == 0) { red[w] = sum; red[4 + w] = ss; }
  __syncthreads();
  sum = red[0] + red[1] + red[2] + red[3];
  ss = red[4] + red[5] + red[6] + red[7];
  const float mean = sum * (1.0f / 512.0f);
  const float var = ss * (1.0f / 512.0f) - mean * mean;
  const float rstd = rsqrtf(var + 1e-5f);
  float o0 = (y0 - mean) * rstd * s[d] + b[d];
  float o1 = (y1 - mean) * rstd * s[d + 1] + b[d + 1];
  *(float2*)(xout + (long)r * 512 + d) = make_float2(o0, o1);
  bf16x2 ob = {(bf16_t)o0, (bf16_t)o1};
  *(bf16x2*)(xbf + (long)r * 512 + d) = ob;
}

// ---------------- exact GELU -> bf16 ----------------
__global__ void k_gelu(const float* __restrict__ in, bf16_t* __restrict__ out, long n4) {
  long stride = (long)gridDim.x * blockDim.x;
  for (long i = (long)blockIdx.x * blockDim.x + threadIdx.x; i < n4; i += stride) {
    float4 v = ((const float4*)in)[i];
    float g0 = 0.5f * v.x * (1.0f + erff(v.x * 0.70710678118654752f));
    float g1 = 0.5f * v.y * (1.0f + erff(v.y * 0.70710678118654752f));
    float g2 = 0.5f * v.z * (1.0f + erff(v.z * 0.70710678118654752f));
    float g3 = 0.5f * v.w * (1.0f + erff(v.w * 0.70710678118654752f));
    bf16x4 o = {(bf16_t)g0, (bf16_t)g1, (bf16_t)g2, (bf16_t)g3};
    ((bf16x4*)out)[i] = o;
  }
}

// ---------------- online top-4 merge over a 4096-col score chunk ----------------
DEVI bool tk_better(float av, int ai, float bv, int bi) {
  return (av > bv) || (av == bv && ai < bi);  // lax.top_k tie-break: lower index
}
DEVI void tk_insert(float* v, int* ix, float nv, int ni) {
  if (!tk_better(nv, ni, v[3], ix[3])) return;
  v[3] = nv; ix[3] = ni;
#pragma unroll
  for (int j = 3; j > 0; --j) {
    if (tk_better(v[j], ix[j], v[j - 1], ix[j - 1])) {
      float tv_ = v[j]; v[j] = v[j - 1]; v[j - 1] = tv_;
      int ti_ = ix[j]; ix[j] = ix[j - 1]; ix[j - 1] = ti_;
    }
  }
}
__global__ void k_topk(const float* __restrict__ sc, const float* __restrict__ sal,
                       int c0, float* __restrict__ tv, int* __restrict__ ti, int first) {
  const int r = blockIdx.x * 4 + (threadIdx.x >> 6);  // one wave per row
  const int lane = threadIdx.x & 63;
  float v[4] = {-1e30f, -1e30f, -1e30f, -1e30f};
  int ix[4] = {0x7fffffff, 0x7fffffff, 0x7fffffff, 0x7fffffff};
  const float* row = sc + (long)r * 4096;
  for (int c = lane; c < 4096; c += 64)
    tk_insert(v, ix, row[c] + sal[c0 + c], c0 + c);
#pragma unroll
  for (int dd = 1; dd < 64; dd <<= 1) {
    float ov[4]; int oi[4];
#pragma unroll
    for (int j = 0; j < 4; ++j) { ov[j] = __shfl_xor(v[j], dd); oi[j] = __shfl_xor(ix[j], dd); }
#pragma unroll
    for (int j = 0; j < 4; ++j) tk_insert(v, ix, ov[j], oi[j]);
  }
  if (lane == 0) {
    float* tvr = tv + (long)r * 4;
    int* tir = ti + (long)r * 4;
    if (!first) {
#pragma unroll
      for (int j = 0; j < 4; ++j) tk_insert(v, ix, tvr[j], tir[j]);
    }
#pragma unroll
    for (int j = 0; j < 4; ++j) { tvr[j] = v[j]; tir[j] = ix[j]; }
  }
}

// ---------------- gather V by top-4, softmax weights, avg over 3 levels ----------------
__global__ void k_read(const float* __restrict__ tv, const int* __restrict__ ti,
                       const float* __restrict__ V0, const float* __restrict__ V1,
                       const float* __restrict__ V2, bf16_t* __restrict__ readb) {
  const int r = blockIdx.x;
  const int d = threadIdx.x * 2;
  float a0 = 0.f, a1 = 0.f;
  const float* Vs[3] = {V0, V1, V2};
#pragma unroll
  for (int lev = 0; lev < 3; ++lev) {
    const float* tvr = tv + ((long)lev * 4096 + r) * 4;
    const int* tir = ti + ((long)lev * 4096 + r) * 4;
    float t0 = tvr[0], t1 = tvr[1], t2 = tvr[2], t3 = tvr[3];
    float m = fmaxf(fmaxf(t0, t1), fmaxf(t2, t3));
    float e0 = __expf(t0 - m), e1 = __expf(t1 - m), e2 = __expf(t2 - m), e3 = __expf(t3 - m);
    float inv = 1.0f / (e0 + e1 + e2 + e3);
    float w4[4] = {e0 * inv, e1 * inv, e2 * inv, e3 * inv};
#pragma unroll
    for (int k = 0; k < 4; ++k) {
      const float* vr = Vs[lev] + (long)tir[k] * 512;
      a0 += w4[k] * vr[d];
      a1 += w4[k] * vr[d + 1];
    }
  }
  bf16x2 o = {(bf16_t)(a0 * (1.0f / 3.0f)), (bf16_t)(a1 * (1.0f / 3.0f))};
  *(bf16x2*)(readb + (long)r * 512 + d) = o;
}

// ---------------- host ----------------
template <typename CT, bool BIAS>
static inline void gemm_launch(hipStream_t st, const bf16_t* A, long long sAb, int lda,
                               const bf16_t* B, long long sBb, int ldb, CT* C,
                               long long sCb, int ldc, const float* bias, int M, int N,
                               int K, int bat, float alpha) {
  dim3 g((N + 127) / 128, M / 128, bat);
  k_gemm_bt<CT, BIAS><<<g, dim3(256), 0, st>>>(A, sAb, lda, B, sBb, ldb, C, sCb, ldc, bias, N, K, alpha);
}

extern "C" void kernel_launch(void* const* d_in, const int* in_sizes, int n_in,
                              void* d_out, int out_size, void* d_ws, size_t ws_size,
                              hipStream_t stream) {
  (void)in_sizes; (void)n_in; (void)out_size; (void)ws_size;
  const int* ids = (const int*)d_in[0];
  const float* tok = (const float*)d_in[1];
  const float* pos = (const float*)d_in[2];
  const float* Wqkv = (const float*)d_in[3];
  const float* bqkv = (const float*)d_in[4];
  const float* Wo = (const float*)d_in[5];
  const float* bo = (const float*)d_in[6];
  const float* ln1s = (const float*)d_in[7];
  const float* ln1b = (const float*)d_in[8];
  const float* W1 = (const float*)d_in[9];
  const float* b1 = (const float*)d_in[10];
  const float* W2 = (const float*)d_in[11];
  const float* b2 = (const float*)d_in[12];
  const float* ln2s = (const float*)d_in[13];
  const float* ln2b = (const float*)d_in[14];
  const float* Wq = (const float*)d_in[15];
  const float* bq = (const float*)d_in[16];
  const float* Wrp = (const float*)d_in[17];
  const float* brp = (const float*)d_in[18];
  const float* lnos = (const float*)d_in[19];
  const float* lnob = (const float*)d_in[20];
  const float* K0 = (const float*)d_in[21];
  const float* V0 = (const float*)d_in[22];
  const float* s0 = (const float*)d_in[23];
  const float* K1 = (const float*)d_in[24];
  const float* V1 = (const float*)d_in[25];
  const float* s1 = (const float*)d_in[26];
  const float* K2 = (const float*)d_in[27];
  const float* V2 = (const float*)d_in[28];
  const float* s2 = (const float*)d_in[29];

  // ---- scratch layout ----
  // Big transients live in d_out (524MB): every read of them finishes before the
  // final lm_head GEMM overwrites d_out. Survivors (tokb, xfb, ...) live in d_ws.
  char* wp = (char*)d_ws;
  auto walloc = [&](size_t bytes) -> char* {
    char* p = wp; wp += (bytes + 255) & ~(size_t)255; return p;
  };
  char* op = (char*)d_out;
  auto oalloc = [&](size_t bytes) -> char* {
    char* p = op; op += (bytes + 255) & ~(size_t)255; return p;
  };

  bf16_t* Wqkvb = (bf16_t*)oalloc(3145728ULL * 2);
  bf16_t* Wob   = (bf16_t*)oalloc(1048576ULL * 2);
  bf16_t* W1b   = (bf16_t*)oalloc(4194304ULL * 2);
  bf16_t* W2b   = (bf16_t*)oalloc(4194304ULL * 2);
  bf16_t* Wqb   = (bf16_t*)oalloc(262144ULL * 2);
  bf16_t* Wrpb  = (bf16_t*)oalloc(262144ULL * 2);
  bf16_t* Kb    = (bf16_t*)oalloc(28672ULL * 512 * 2);   // K0|K1|K2 bf16
  float*  qkv   = (float*)oalloc(4096ULL * 1536 * 4);
  bf16_t* attb  = (bf16_t*)oalloc(8ULL * 2048 * 2048 * 2);  // per-batch att, 67MB
  float*  scoreb = (float*)attb;                            // reused: 4096x4096 f32 scores
  float*  hbuf  = (float*)oalloc(4096ULL * 2048 * 4);
  bf16_t* hb    = (bf16_t*)oalloc(4096ULL * 2048 * 2);

  bf16_t* tokb = (bf16_t*)walloc(16384000ULL * 2);  // must survive to lm_head
  float*  x    = (float*)walloc(4096ULL * 512 * 4);
  bf16_t* xb   = (bf16_t*)walloc(4096ULL * 512 * 2);
  bf16_t* qh   = (bf16_t*)walloc(2097152ULL * 2);
  bf16_t* kh   = (bf16_t*)walloc(2097152ULL * 2);
  bf16_t* vt   = (bf16_t*)walloc(2097152ULL * 2);
  bf16_t* attob = (bf16_t*)walloc(4096ULL * 512 * 2);
  float*  delta = (float*)walloc(4096ULL * 512 * 4);
  bf16_t* qmb  = (bf16_t*)walloc(4096ULL * 512 * 2);
  bf16_t* readb = (bf16_t*)walloc(4096ULL * 512 * 2);
  float*  tval = (float*)walloc(3ULL * 4096 * 4 * 4);
  int*    tidx = (int*)walloc(3ULL * 4096 * 4 * 4);
  bf16_t* xfb  = (bf16_t*)walloc(4096ULL * 512 * 2);

  auto f2b = [&](const float* in, bf16_t* o, long n) {
    k_f2b<<<1024, 256, 0, stream>>>(in, o, n / 4);
  };
  f2b(tok, tokb, 16384000L);
  f2b(Wqkv, Wqkvb, 3145728L);
  f2b(Wo, Wob, 1048576L);
  f2b(W1, W1b, 4194304L);
  f2b(W2, W2b, 4194304L);
  f2b(Wq, Wqb, 262144L);
  f2b(Wrp, Wrpb, 262144L);
  f2b(K0, Kb, 8388608L);
  f2b(K1, Kb + 8388608L, 4194304L);
  f2b(K2, Kb + 12582912L, 2097152L);

  k_embed<<<4096, 256, 0, stream>>>(ids, tok, pos, x, xb);

  for (int i = 0; i < 4; ++i) {
    gemm_launch<float, true>(stream, xb, 0, 512, Wqkvb + (long long)i * 786432, 0, 512,
                             qkv, 0, 1536, bqkv + i * 1536, 4096, 1536, 512, 1, 1.0f);
    k_qkv_split<<<8192, 256, 0, stream>>>(qkv, qh, kh, vt);
    for (int b = 0; b < 2; ++b) {
      const bf16_t* qb_ = qh + (long long)b * 8 * 2048 * 64;
      const bf16_t* kb_ = kh + (long long)b * 8 * 2048 * 64;
      // S = (q*0.125) @ k^T, per head (z=8), bf16 out
      gemm_launch<bf16_t, false>(stream, qb_, 2048LL * 64, 64, kb_, 2048LL * 64, 64,
                                 attb, 2048LL * 2048, 2048, nullptr, 2048, 2048, 64, 8, 1.0f);
      k_softmax<<<16384, 256, 0, stream>>>(attb);
      // O = att @ V   (V as [64, T] so same B^T GEMM; C strided into [T, D] at head cols)
      gemm_launch<bf16_t, false>(stream, attb, 2048LL * 2048, 2048,
                                 vt + (long long)b * 8 * 64 * 2048, 64LL * 2048, 2048,
                                 attob + (long long)b * 2048 * 512, 64, 512, nullptr,
                                 2048, 64, 2048, 8, 1.0f);
    }
    gemm_launch<float, true>(stream, attob, 0, 512, Wob + (long long)i * 262144, 0, 512,
                             delta, 0, 512, bo + i * 512, 4096, 512, 512, 1, 1.0f);
    k_ln<<<4096, 256, 0, stream>>>(x, delta, ln1s + i * 512, ln1b + i * 512, x, xb);
    gemm_launch<float, true>(stream, xb, 0, 512, W1b + (long long)i * 1048576, 0, 512,
                             hbuf, 0, 2048, b1 + i * 2048, 4096, 2048, 512, 1, 1.0f);
    k_gelu<<<2048, 256, 0, stream>>>(hbuf, hb, 2097152L);
    gemm_launch<float, true>(stream, hb, 0, 2048, W2b + (long long)i * 1048576, 0, 2048,
                             delta, 0, 512, b2 + i * 512, 4096, 512, 2048, 1, 1.0f);
    k_ln<<<4096, 256, 0, stream>>>(x, delta, ln2s + i * 512, ln2b + i * 512, x, xb);
  }

  // hierarchical memory read: qm = (x@Wq^T + bq) * (1/sqrt(512)), bf16
  gemm_launch<bf16_t, true>(stream, xb, 0, 512, Wqb, 0, 512, qmb, 0, 512, bq,
                            4096, 512, 512, 1, 0.044194173824159216f);
  const float* sal[3] = {s0, s1, s2};
  const int slots[3] = {16384, 8192, 4096};
  long koff = 0;
  for (int lev = 0; lev < 3; ++lev) {
    int nch = slots[lev] / 4096;
    for (int c = 0; c < nch; ++c) {
      gemm_launch<float, false>(stream, qmb, 0, 512, Kb + (koff + (long)c * 4096) * 512, 0, 512,
                                scoreb, 0, 4096, nullptr, 4096, 4096, 512, 1, 1.0f);
      k_topk<<<1024, 256, 0, stream>>>(scoreb, sal[lev], c * 4096,
                                       tval + (long)lev * 16384, tidx + (long)lev * 16384,
                                       c == 0 ? 1 : 0);
    }
    koff += slots[lev];
  }
  k_read<<<4096, 256, 0, stream>>>(tval, tidx, V0, V1, V2, readb);
  gemm_launch<float, true>(stream, readb, 0, 512, Wrpb, 0, 512, delta, 0, 512, brp,
                           4096, 512, 512, 1, 1.0f);
  k_ln<<<4096, 256, 0, stream>>>(x, delta, lnos, lnob, x, xfb);
  // logits = x @ tok_embed^T  -> d_out (f32), overwrites all scratch that lived there
  gemm_launch<float, false>(stream, xfb, 0, 512, tokb, 0, 512, (float*)d_out, 0, 32000,
                            nullptr, 4096, 32000, 512, 1, 1.0f);
}

// Round 2
// 1536.912 us; speedup vs baseline: 1.3790x; 1.3790x over previous
//
#include <hip/hip_runtime.h>
#include <cstdint>

typedef __bf16 bf16_t;
typedef __bf16 bf16x2 __attribute__((ext_vector_type(2)));
typedef __bf16 bf16x4 __attribute__((ext_vector_type(4)));
typedef __bf16 bf16x8 __attribute__((ext_vector_type(8)));
typedef float f32x4 __attribute__((ext_vector_type(4)));

#define DEVI static __device__ __forceinline__

// async global->LDS, 16B per lane; LDS dest = wave-uniform base + lane*16
DEVI void g2l16(const void* g, void* l) {
  __builtin_amdgcn_global_load_lds((__attribute__((address_space(1))) void*)g,
                                   (__attribute__((address_space(3))) void*)l,
                                   16, 0, 0);
}

// ---------------- f32 -> bf16 convert ----------------
__global__ void k_f2b(const float* __restrict__ in, bf16_t* __restrict__ out, long n4) {
  long stride = (long)gridDim.x * blockDim.x;
  for (long i = (long)blockIdx.x * blockDim.x + threadIdx.x; i < n4; i += stride) {
    float4 v = ((const float4*)in)[i];
    bf16x4 o = {(bf16_t)v.x, (bf16_t)v.y, (bf16_t)v.z, (bf16_t)v.w};
    ((bf16x4*)out)[i] = o;
  }
}

// ---------------- embedding ----------------
__global__ void k_embed(const int* __restrict__ ids, const float* __restrict__ tok,
                        const float* __restrict__ pos, float* __restrict__ x,
                        bf16_t* __restrict__ xb) {
  int r = blockIdx.x;
  int t = r & 2047;
  long id = ids[r];
  int d = threadIdx.x * 2;
  float2 a = *(const float2*)(tok + id * 512 + d);
  float2 p = *(const float2*)(pos + (long)t * 512 + d);
  float o0 = a.x + p.x, o1 = a.y + p.y;
  *(float2*)(x + (long)r * 512 + d) = make_float2(o0, o1);
  bf16x2 ob = {(bf16_t)o0, (bf16_t)o1};
  *(bf16x2*)(xb + (long)r * 512 + d) = ob;
}

// ---------------- batched GEMM: C[M,N] = (A[M,K] @ B[N,K]^T + bias) * alpha ----------------
template <typename CT, bool BIAS>
__global__ __launch_bounds__(256, 2) void k_gemm_bt(
    const bf16_t* __restrict__ A, long long sAb, int lda,
    const bf16_t* __restrict__ B, long long sBb, int ldb,
    CT* __restrict__ C, long long sCb, int ldc,
    const float* __restrict__ bias, int N, int K, float alpha) {
  __shared__ bf16_t As[4096];  // [128][32]
  __shared__ bf16_t Bs[4096];  // [128][32]
  const int tid = threadIdx.x;
  const int lane = tid & 63;
  const int w = tid >> 6;
  const int wm = w >> 1, wn = w & 1;
  const long long m0 = (long long)blockIdx.y * 128;
  const int n0 = blockIdx.x * 128;
  A += (long long)blockIdx.z * sAb;
  B += (long long)blockIdx.z * sBb;
  C += (long long)blockIdx.z * sCb;

  f32x4 acc[4][4];
#pragma unroll
  for (int m = 0; m < 4; ++m)
#pragma unroll
    for (int n = 0; n < 4; ++n) acc[m][n] = (f32x4){0.f, 0.f, 0.f, 0.f};

  const int srow = tid >> 2;
  const int scol = (tid & 3) * 8;
  const int fr = lane & 15;
  const int kg = (lane >> 4) * 8;

  for (int k0 = 0; k0 < K; k0 += 32) {
#pragma unroll
    for (int p = 0; p < 2; ++p) {
      const bf16_t* ga = A + (m0 + p * 64 + srow) * (long long)lda + (k0 + scol);
      g2l16(ga, As + p * 2048 + w * 512);
      int rb = n0 + p * 64 + srow;
      if (rb >= N) rb = N - 1;
      const bf16_t* gb = B + (long long)rb * ldb + (k0 + scol);
      g2l16(gb, Bs + p * 2048 + w * 512);
    }
    __syncthreads();
    bf16x8 fa[4], fb[4];
#pragma unroll
    for (int m = 0; m < 4; ++m)
      fa[m] = *(const bf16x8*)(As + (wm * 64 + m * 16 + fr) * 32 + kg);
#pragma unroll
    for (int n = 0; n < 4; ++n)
      fb[n] = *(const bf16x8*)(Bs + (wn * 64 + n * 16 + fr) * 32 + kg);
#pragma unroll
    for (int m = 0; m < 4; ++m)
#pragma unroll
      for (int n = 0; n < 4; ++n)
        acc[m][n] = __builtin_amdgcn_mfma_f32_16x16x32_bf16(fa[m], fb[n], acc[m][n], 0, 0, 0);
    __syncthreads();
  }

  const int r0 = (lane >> 4) * 4;
#pragma unroll
  for (int n = 0; n < 4; ++n) {
    const int col = n0 + wn * 64 + n * 16 + fr;
    if (col >= N) continue;
    const float bv = BIAS ? bias[col] : 0.0f;
#pragma unroll
    for (int m = 0; m < 4; ++m) {
      const long long row = m0 + wm * 64 + m * 16 + r0;
#pragma unroll
      for (int r = 0; r < 4; ++r) {
        float v = (acc[m][n][r] + bv) * alpha;
        C[(row + r) * (long long)ldc + col] = (CT)v;
      }
    }
  }
}

// ---------------- fused flash attention ----------------
// grid (16 qtiles, 16 bh), 256 thr. Q pre-scaled. out[b*2048+t][512] at head cols.
__global__ __launch_bounds__(256, 2) void k_flash(
    const bf16_t* __restrict__ qh, const bf16_t* __restrict__ kh,
    const bf16_t* __restrict__ vt, bf16_t* __restrict__ out) {
  __shared__ bf16_t Ks[128 * 64];   // [kv][d], chunks XOR-swizzled by row
  __shared__ bf16_t Vs[64 * 128];   // [d][kv], chunks XOR-swizzled by row
  __shared__ bf16_t Ps[4 * 32 * 128];
  const int tid = threadIdx.x;
  const int lane = tid & 63;
  const int w = tid >> 6;
  const int bh = blockIdx.y;
  const int q0 = blockIdx.x * 128;
  const int fr = lane & 15;
  const int g4 = lane >> 4;
  const int kg = g4 * 8;

  bf16x8 qf[2][2];
  {
    const bf16_t* qb = qh + ((long long)bh * 2048 + q0 + w * 32) * 64;
#pragma unroll
    for (int m = 0; m < 2; ++m)
#pragma unroll
      for (int ks = 0; ks < 2; ++ks)
        qf[m][ks] = *(const bf16x8*)(qb + (m * 16 + fr) * 64 + ks * 32 + kg);
  }

  f32x4 oacc[2][4];
#pragma unroll
  for (int m = 0; m < 2; ++m)
#pragma unroll
    for (int n = 0; n < 4; ++n) oacc[m][n] = (f32x4){0.f, 0.f, 0.f, 0.f};
  float mi[8], li[8];
#pragma unroll
  for (int j = 0; j < 8; ++j) { mi[j] = -1e30f; li[j] = 0.f; }

  char* PsW = (char*)(Ps + w * 32 * 128);
  const bf16_t* kbase = kh + (long long)bh * 2048 * 64;
  const bf16_t* vbase = vt + (long long)bh * 64 * 2048;

  for (int kt = 0; kt < 16; ++kt) {
    // stage K tile [128][64] (src col chunk pre-swizzled so swizzled read is linear data)
#pragma unroll
    for (int i = 0; i < 4; ++i) {
      int row = (w * 4 + i) * 8 + (lane >> 3);
      int c = lane & 7;
      g2l16(kbase + ((long long)(kt * 128 + row)) * 64 + (c ^ (row & 7)) * 8,
            Ks + (w * 4 + i) * 512);
    }
    // stage V^T tile [64][128]
#pragma unroll
    for (int i = 0; i < 4; ++i) {
      int d = w * 16 + i * 4 + (lane >> 4);
      int c = lane & 15;
      g2l16(vbase + (long long)d * 2048 + kt * 128 + ((c ^ (d & 7)) * 8),
            Vs + (w * 16 + i * 4) * 128);
    }
    __syncthreads();

    // S = Q @ K^T  (wave's 32 rows x 128 kv)
    f32x4 s[2][8];
#pragma unroll
    for (int m = 0; m < 2; ++m)
#pragma unroll
      for (int n = 0; n < 8; ++n) s[m][n] = (f32x4){0.f, 0.f, 0.f, 0.f};
#pragma unroll
    for (int ks = 0; ks < 2; ++ks) {
#pragma unroll
      for (int n = 0; n < 8; ++n) {
        int row = n * 16 + fr;
        bf16x8 kf = *(const bf16x8*)((const char*)Ks + row * 128 +
                                     ((ks * 64 + kg * 2) ^ ((row & 7) << 4)));
#pragma unroll
        for (int m = 0; m < 2; ++m)
          s[m][n] = __builtin_amdgcn_mfma_f32_16x16x32_bf16(qf[m][ks], kf, s[m][n], 0, 0, 0);
      }
    }

    // online softmax per row; P -> swizzled LDS (bf16)
#pragma unroll
    for (int m = 0; m < 2; ++m) {
#pragma unroll
      for (int r = 0; r < 4; ++r) {
        float pm = -1e30f;
#pragma unroll
        for (int n = 0; n < 8; ++n) pm = fmaxf(pm, s[m][n][r]);
        pm = fmaxf(pm, __shfl_xor(pm, 1));
        pm = fmaxf(pm, __shfl_xor(pm, 2));
        pm = fmaxf(pm, __shfl_xor(pm, 4));
        pm = fmaxf(pm, __shfl_xor(pm, 8));
        const int ri = m * 4 + r;
        const float mnew = fmaxf(mi[ri], pm);
        const float alpha = __expf(mi[ri] - mnew);
        mi[ri] = mnew;
        const int lr = m * 16 + g4 * 4 + r;
        const int sw = (lr & 7) << 4;
        float rs = 0.f;
#pragma unroll
        for (int n = 0; n < 8; ++n) {
          float p = __expf(s[m][n][r] - mnew);
          rs += p;
          *(bf16_t*)(PsW + lr * 256 + (((n * 16 + fr) * 2) ^ sw)) = (bf16_t)p;
        }
        rs += __shfl_xor(rs, 1);
        rs += __shfl_xor(rs, 2);
        rs += __shfl_xor(rs, 4);
        rs += __shfl_xor(rs, 8);
        li[ri] = li[ri] * alpha + rs;
#pragma unroll
        for (int n = 0; n < 4; ++n) oacc[m][n][r] *= alpha;
      }
    }

    // O += P @ V  (per-wave P, shared V^T)
#pragma unroll
    for (int ks = 0; ks < 4; ++ks) {
      bf16x8 pa[2];
#pragma unroll
      for (int m = 0; m < 2; ++m) {
        int row = m * 16 + fr;
        pa[m] = *(const bf16x8*)(PsW + row * 256 +
                                 ((ks * 64 + kg * 2) ^ ((row & 7) << 4)));
      }
#pragma unroll
      for (int n = 0; n < 4; ++n) {
        int d = n * 16 + fr;
        bf16x8 vf = *(const bf16x8*)((const char*)Vs + d * 256 +
                                     ((ks * 64 + kg * 2) ^ ((d & 7) << 4)));
#pragma unroll
        for (int m = 0; m < 2; ++m)
          oacc[m][n] = __builtin_amdgcn_mfma_f32_16x16x32_bf16(pa[m], vf, oacc[m][n], 0, 0, 0);
      }
    }
    __syncthreads();
  }

  const int b = bh >> 3, h = bh & 7;
  bf16_t* ob = out + ((long long)b * 2048 + q0 + w * 32) * 512 + h * 64;
#pragma unroll
  for (int m = 0; m < 2; ++m)
#pragma unroll
    for (int r = 0; r < 4; ++r) {
      float inv = 1.0f / li[m * 4 + r];
#pragma unroll
      for (int n = 0; n < 4; ++n)
        ob[(m * 16 + g4 * 4 + r) * 512 + n * 16 + fr] = (bf16_t)(oacc[m][n][r] * inv);
    }
}

// ---------------- qkv split (bf16 in): q*0.125 -> [bh,t,hd]; k; v -> [bh,hd,t] ----------------
__global__ void k_qkv_split(const bf16_t* __restrict__ qkv, bf16_t* __restrict__ qh,
                            bf16_t* __restrict__ kh, bf16_t* __restrict__ vt) {
  long i = (long)blockIdx.x * 256 + threadIdx.x;
  int r = (int)(i >> 9);
  int d = (int)(i & 511);
  int b = r >> 11, t = r & 2047;
  int h = d >> 6, hd = d & 63;
  const bf16_t* src = qkv + (long)r * 1536;
  long bh = (long)b * 8 + h;
  qh[(bh * 2048 + t) * 64 + hd] = (bf16_t)((float)src[d] * 0.125f);
  kh[(bh * 2048 + t) * 64 + hd] = src[512 + d];
  vt[(bh * 64 + hd) * 2048 + t] = src[1024 + d];
}

// ---------------- LN(xin + delta) * s + b -> xout (f32) + xbf (bf16), D=512 ----------------
__global__ void k_ln(const float* __restrict__ xin, const float* __restrict__ delta,
                     const float* __restrict__ s, const float* __restrict__ b,
                     float* __restrict__ xout, bf16_t* __restrict__ xbf) {
  __shared__ float red[8];
  const int r = blockIdx.x;
  const int tid = threadIdx.x;
  const int d = tid * 2;
  const int lane = tid & 63, w = tid >> 6;
  float2 xi = *(const float2*)(xin + (long)r * 512 + d);
  float2 de = *(const float2*)(delta + (long)r * 512 + d);
  float y0 = xi.x + de.x, y1 = xi.y + de.y;
  float sum = y0 + y1, ss = y0 * y0 + y1 * y1;
#pragma unroll
  for (int o = 32; o > 0; o >>= 1) { sum += __shfl_xor(sum, o); ss += __shfl_xor(ss, o); }
  if (lane == 0) { red[w] = sum; red[4 + w] = ss; }
  __syncthreads();
  sum = red[0] + red[1] + red[2] + red[3];
  ss = red[4] + red[5] + red[6] + red[7];
  const float mean = sum * (1.0f / 512.0f);
  const float var = ss * (1.0f / 512.0f) - mean * mean;
  const float rstd = rsqrtf(var + 1e-5f);
  float o0 = (y0 - mean) * rstd * s[d] + b[d];
  float o1 = (y1 - mean) * rstd * s[d + 1] + b[d + 1];
  *(float2*)(xout + (long)r * 512 + d) = make_float2(o0, o1);
  bf16x2 ob = {(bf16_t)o0, (bf16_t)o1};
  *(bf16x2*)(xbf + (long)r * 512 + d) = ob;
}

// ---------------- exact GELU (bf16 in -> bf16 out) ----------------
__global__ void k_gelu(const bf16_t* __restrict__ in, bf16_t* __restrict__ out, long n8) {
  long stride = (long)gridDim.x * blockDim.x;
  for (long i = (long)blockIdx.x * blockDim.x + threadIdx.x; i < n8; i += stride) {
    bf16x8 v = ((const bf16x8*)in)[i];
    bf16x8 o;
#pragma unroll
    for (int j = 0; j < 8; ++j) {
      float f = (float)v[j];
      o[j] = (bf16_t)(0.5f * f * (1.0f + erff(f * 0.70710678118654752f)));
    }
    ((bf16x8*)out)[i] = o;
  }
}

// ---------------- top-4 over bf16 score row + f32 salience ----------------
DEVI bool tk_better(float av, int ai, float bv, int bi) {
  return (av > bv) || (av == bv && ai < bi);
}
DEVI void tk_insert(float* v, int* ix, float nv, int ni) {
  if (!tk_better(nv, ni, v[3], ix[3])) return;
  v[3] = nv; ix[3] = ni;
#pragma unroll
  for (int j = 3; j > 0; --j) {
    if (tk_better(v[j], ix[j], v[j - 1], ix[j - 1])) {
      float tv_ = v[j]; v[j] = v[j - 1]; v[j - 1] = tv_;
      int ti_ = ix[j]; ix[j] = ix[j - 1]; ix[j - 1] = ti_;
    }
  }
}
__global__ void k_topk(const bf16_t* __restrict__ sc, const float* __restrict__ sal,
                       int ncol, float* __restrict__ tv, int* __restrict__ ti) {
  const int r = blockIdx.x * 4 + (threadIdx.x >> 6);
  const int lane = threadIdx.x & 63;
  float v[4] = {-1e30f, -1e30f, -1e30f, -1e30f};
  int ix[4] = {0x7fffffff, 0x7fffffff, 0x7fffffff, 0x7fffffff};
  const bf16_t* row = sc + (long)r * ncol;
  for (int c0 = lane * 8; c0 < ncol; c0 += 512) {
    bf16x8 sv = *(const bf16x8*)(row + c0);
    float4 s0 = *(const float4*)(sal + c0);
    float4 s1 = *(const float4*)(sal + c0 + 4);
    tk_insert(v, ix, (float)sv[0] + s0.x, c0 + 0);
    tk_insert(v, ix, (float)sv[1] + s0.y, c0 + 1);
    tk_insert(v, ix, (float)sv[2] + s0.z, c0 + 2);
    tk_insert(v, ix, (float)sv[3] + s0.w, c0 + 3);
    tk_insert(v, ix, (float)sv[4] + s1.x, c0 + 4);
    tk_insert(v, ix, (float)sv[5] + s1.y, c0 + 5);
    tk_insert(v, ix, (float)sv[6] + s1.z, c0 + 6);
    tk_insert(v, ix, (float)sv[7] + s1.w, c0 + 7);
  }
#pragma unroll
  for (int dd = 1; dd < 64; dd <<= 1) {
    float ov[4]; int oi[4];
#pragma unroll
    for (int j = 0; j < 4; ++j) { ov[j] = __shfl_xor(v[j], dd); oi[j] = __shfl_xor(ix[j], dd); }
#pragma unroll
    for (int j = 0; j < 4; ++j) tk_insert(v, ix, ov[j], oi[j]);
  }
  if (lane == 0) {
#pragma unroll
    for (int j = 0; j < 4; ++j) { tv[(long)r * 4 + j] = v[j]; ti[(long)r * 4 + j] = ix[j]; }
  }
}

// ---------------- gather V by top-4, softmax weights, avg over 3 levels ----------------
__global__ void k_read(const float* __restrict__ tv, const int* __restrict__ ti,
                       const float* __restrict__ V0, const float* __restrict__ V1,
                       const float* __restrict__ V2, bf16_t* __restrict__ readb) {
  const int r = blockIdx.x;
  const int d = threadIdx.x * 2;
  float a0 = 0.f, a1 = 0.f;
  const float* Vs[3] = {V0, V1, V2};
#pragma unroll
  for (int lev = 0; lev < 3; ++lev) {
    const float* tvr = tv + ((long)lev * 4096 + r) * 4;
    const int* tir = ti + ((long)lev * 4096 + r) * 4;
    float t0 = tvr[0], t1 = tvr[1], t2 = tvr[2], t3 = tvr[3];
    float m = fmaxf(fmaxf(t0, t1), fmaxf(t2, t3));
    float e0 = __expf(t0 - m), e1 = __expf(t1 - m), e2 = __expf(t2 - m), e3 = __expf(t3 - m);
    float inv = 1.0f / (e0 + e1 + e2 + e3);
    float w4[4] = {e0 * inv, e1 * inv, e2 * inv, e3 * inv};
#pragma unroll
    for (int k = 0; k < 4; ++k) {
      const float* vr = Vs[lev] + (long)tir[k] * 512;
      a0 += w4[k] * vr[d];
      a1 += w4[k] * vr[d + 1];
    }
  }
  bf16x2 o = {(bf16_t)(a0 * (1.0f / 3.0f)), (bf16_t)(a1 * (1.0f / 3.0f))};
  *(bf16x2*)(readb + (long)r * 512 + d) = o;
}

// ---------------- host ----------------
template <typename CT, bool BIAS>
static inline void gemm_launch(hipStream_t st, const bf16_t* A, long long sAb, int lda,
                               const bf16_t* B, long long sBb, int ldb, CT* C,
                               long long sCb, int ldc, const float* bias, int M, int N,
                               int K, int bat, float alpha) {
  dim3 g((N + 127) / 128, M / 128, bat);
  k_gemm_bt<CT, BIAS><<<g, dim3(256), 0, st>>>(A, sAb, lda, B, sBb, ldb, C, sCb, ldc, bias, N, K, alpha);
}

extern "C" void kernel_launch(void* const* d_in, const int* in_sizes, int n_in,
                              void* d_out, int out_size, void* d_ws, size_t ws_size,
                              hipStream_t stream) {
  (void)in_sizes; (void)n_in; (void)out_size; (void)ws_size;
  const int* ids = (const int*)d_in[0];
  const float* tok = (const float*)d_in[1];
  const float* pos = (const float*)d_in[2];
  const float* Wqkv = (const float*)d_in[3];
  const float* bqkv = (const float*)d_in[4];
  const float* Wo = (const float*)d_in[5];
  const float* bo = (const float*)d_in[6];
  const float* ln1s = (const float*)d_in[7];
  const float* ln1b = (const float*)d_in[8];
  const float* W1 = (const float*)d_in[9];
  const float* b1 = (const float*)d_in[10];
  const float* W2 = (const float*)d_in[11];
  const float* b2 = (const float*)d_in[12];
  const float* ln2s = (const float*)d_in[13];
  const float* ln2b = (const float*)d_in[14];
  const float* Wq = (const float*)d_in[15];
  const float* bq = (const float*)d_in[16];
  const float* Wrp = (const float*)d_in[17];
  const float* brp = (const float*)d_in[18];
  const float* lnos = (const float*)d_in[19];
  const float* lnob = (const float*)d_in[20];
  const float* K0 = (const float*)d_in[21];
  const float* V0 = (const float*)d_in[22];
  const float* s0 = (const float*)d_in[23];
  const float* K1 = (const float*)d_in[24];
  const float* V1 = (const float*)d_in[25];
  const float* s1 = (const float*)d_in[26];
  const float* K2 = (const float*)d_in[27];
  const float* V2 = (const float*)d_in[28];
  const float* s2 = (const float*)d_in[29];

  char* wp = (char*)d_ws;
  auto walloc = [&](size_t bytes) -> char* {
    char* p = wp; wp += (bytes + 255) & ~(size_t)255; return p;
  };
  char* op = (char*)d_out;
  auto oalloc = [&](size_t bytes) -> char* {
    char* p = op; op += (bytes + 255) & ~(size_t)255; return p;
  };

  // transients in d_out (all reads complete before lm_head overwrites d_out)
  bf16_t* Wqkvb = (bf16_t*)oalloc(3145728ULL * 2);
  bf16_t* Wob   = (bf16_t*)oalloc(1048576ULL * 2);
  bf16_t* W1b   = (bf16_t*)oalloc(4194304ULL * 2);
  bf16_t* W2b   = (bf16_t*)oalloc(4194304ULL * 2);
  bf16_t* Wqb   = (bf16_t*)oalloc(262144ULL * 2);
  bf16_t* Wrpb  = (bf16_t*)oalloc(262144ULL * 2);
  bf16_t* Kb    = (bf16_t*)oalloc(28672ULL * 512 * 2);
  bf16_t* qkvb  = (bf16_t*)oalloc(4096ULL * 1536 * 2);
  bf16_t* hpre  = (bf16_t*)oalloc(4096ULL * 2048 * 2);
  bf16_t* hb    = (bf16_t*)oalloc(4096ULL * 2048 * 2);
  bf16_t* scb   = (bf16_t*)oalloc(4096ULL * 16384 * 2);

  // survivors in d_ws
  bf16_t* tokb = (bf16_t*)walloc(16384000ULL * 2);
  float*  x    = (float*)walloc(4096ULL * 512 * 4);
  bf16_t* xb   = (bf16_t*)walloc(4096ULL * 512 * 2);
  bf16_t* qh   = (bf16_t*)walloc(2097152ULL * 2);
  bf16_t* kh   = (bf16_t*)walloc(2097152ULL * 2);
  bf16_t* vt   = (bf16_t*)walloc(2097152ULL * 2);
  bf16_t* attob = (bf16_t*)walloc(4096ULL * 512 * 2);
  float*  delta = (float*)walloc(4096ULL * 512 * 4);
  bf16_t* qmb  = (bf16_t*)walloc(4096ULL * 512 * 2);
  bf16_t* readb = (bf16_t*)walloc(4096ULL * 512 * 2);
  float*  tval = (float*)walloc(3ULL * 4096 * 4 * 4);
  int*    tidx = (int*)walloc(3ULL * 4096 * 4 * 4);
  bf16_t* xfb  = (bf16_t*)walloc(4096ULL * 512 * 2);

  auto f2b = [&](const float* in, bf16_t* o, long n) {
    k_f2b<<<1024, 256, 0, stream>>>(in, o, n / 4);
  };
  f2b(tok, tokb, 16384000L);
  f2b(Wqkv, Wqkvb, 3145728L);
  f2b(Wo, Wob, 1048576L);
  f2b(W1, W1b, 4194304L);
  f2b(W2, W2b, 4194304L);
  f2b(Wq, Wqb, 262144L);
  f2b(Wrp, Wrpb, 262144L);
  f2b(K0, Kb, 8388608L);
  f2b(K1, Kb + 8388608L, 4194304L);
  f2b(K2, Kb + 12582912L, 2097152L);

  k_embed<<<4096, 256, 0, stream>>>(ids, tok, pos, x, xb);

  for (int i = 0; i < 4; ++i) {
    gemm_launch<bf16_t, true>(stream, xb, 0, 512, Wqkvb + (long long)i * 786432, 0, 512,
                              qkvb, 0, 1536, bqkv + i * 1536, 4096, 1536, 512, 1, 1.0f);
    k_qkv_split<<<8192, 256, 0, stream>>>(qkvb, qh, kh, vt);
    k_flash<<<dim3(16, 16), 256, 0, stream>>>(qh, kh, vt, attob);
    gemm_launch<float, true>(stream, attob, 0, 512, Wob + (long long)i * 262144, 0, 512,
                             delta, 0, 512, bo + i * 512, 4096, 512, 512, 1, 1.0f);
    k_ln<<<4096, 256, 0, stream>>>(x, delta, ln1s + i * 512, ln1b + i * 512, x, xb);
    gemm_launch<bf16_t, true>(stream, xb, 0, 512, W1b + (long long)i * 1048576, 0, 512,
                              hpre, 0, 2048, b1 + i * 2048, 4096, 2048, 512, 1, 1.0f);
    k_gelu<<<2048, 256, 0, stream>>>(hpre, hb, 1048576L);
    gemm_launch<float, true>(stream, hb, 0, 2048, W2b + (long long)i * 1048576, 0, 2048,
                             delta, 0, 512, b2 + i * 512, 4096, 512, 2048, 1, 1.0f);
    k_ln<<<4096, 256, 0, stream>>>(x, delta, ln2s + i * 512, ln2b + i * 512, x, xb);
  }

  // memory path: qm = (x@Wq^T + bq)/sqrt(512) in bf16
  gemm_launch<bf16_t, true>(stream, xb, 0, 512, Wqb, 0, 512, qmb, 0, 512, bq,
                            4096, 512, 512, 1, 0.044194173824159216f);
  const float* sal[3] = {s0, s1, s2};
  const int slots[3] = {16384, 8192, 4096};
  long koff = 0;
  for (int lev = 0; lev < 3; ++lev) {
    gemm_launch<bf16_t, false>(stream, qmb, 0, 512, Kb + koff * 512, 0, 512,
                               scb, 0, slots[lev], nullptr, 4096, slots[lev], 512, 1, 1.0f);
    k_topk<<<1024, 256, 0, stream>>>(scb, sal[lev], slots[lev],
                                     tval + (long)lev * 16384, tidx + (long)lev * 16384);
    koff += slots[lev];
  }
  k_read<<<4096, 256, 0, stream>>>(tval, tidx, V0, V1, V2, readb);
  gemm_launch<float, true>(stream, readb, 0, 512, Wrpb, 0, 512, delta, 0, 512, brp,
                           4096, 512, 512, 1, 1.0f);
  k_ln<<<4096, 256, 0, stream>>>(x, delta, lnos, lnob, x, xfb);
  gemm_launch<float, false>(stream, xfb, 0, 512, tokb, 0, 512, (float*)d_out, 0, 32000,
                            nullptr, 4096, 32000, 512, 1, 1.0f);
}

// Round 3
// 1434.266 us; speedup vs baseline: 1.4777x; 1.0716x over previous
//
#include <hip/hip_runtime.h>
#include <cstdint>

typedef __bf16 bf16_t;
typedef __bf16 bf16x2 __attribute__((ext_vector_type(2)));
typedef __bf16 bf16x4 __attribute__((ext_vector_type(4)));
typedef __bf16 bf16x8 __attribute__((ext_vector_type(8)));
typedef float f32x4 __attribute__((ext_vector_type(4)));

#define DEVI static __device__ __forceinline__

// async global->LDS, 16B per lane; LDS dest = wave-uniform base + lane*16
DEVI void g2l16(const void* g, void* l) {
  __builtin_amdgcn_global_load_lds((__attribute__((address_space(1))) void*)g,
                                   (__attribute__((address_space(3))) void*)l,
                                   16, 0, 0);
}

// ---------------- f32 -> bf16 convert ----------------
__global__ void k_f2b(const float* __restrict__ in, bf16_t* __restrict__ out, long n4) {
  long stride = (long)gridDim.x * blockDim.x;
  for (long i = (long)blockIdx.x * blockDim.x + threadIdx.x; i < n4; i += stride) {
    float4 v = ((const float4*)in)[i];
    bf16x4 o = {(bf16_t)v.x, (bf16_t)v.y, (bf16_t)v.z, (bf16_t)v.w};
    ((bf16x4*)out)[i] = o;
  }
}

// ---------------- embedding ----------------
__global__ void k_embed(const int* __restrict__ ids, const float* __restrict__ tok,
                        const float* __restrict__ pos, float* __restrict__ x,
                        bf16_t* __restrict__ xb) {
  int r = blockIdx.x;
  int t = r & 2047;
  long id = ids[r];
  int d = threadIdx.x * 2;
  float2 a = *(const float2*)(tok + id * 512 + d);
  float2 p = *(const float2*)(pos + (long)t * 512 + d);
  float o0 = a.x + p.x, o1 = a.y + p.y;
  *(float2*)(x + (long)r * 512 + d) = make_float2(o0, o1);
  bf16x2 ob = {(bf16_t)o0, (bf16_t)o1};
  *(bf16x2*)(xb + (long)r * 512 + d) = ob;
}

DEVI float gelu_f(float f) {
  return 0.5f * f * (1.0f + erff(f * 0.70710678118654752f));
}

// ---------------- 128x128 GEMM: C[M,N] = (A[M,K] @ B[N,K]^T + bias) * alpha ----------------
// EPI: 0 = plain store, 1 = qkv split (q*0.125->qh, k->kh, v->vt), 2 = gelu -> C(bf16)
template <typename CT, bool BIAS, int EPI>
__global__ __launch_bounds__(256, 2) void k_gemm_bt(
    const bf16_t* __restrict__ A, int lda, const bf16_t* __restrict__ B, int ldb,
    CT* __restrict__ C, int ldc, const float* __restrict__ bias, int K, float alpha,
    bf16_t* __restrict__ qh, bf16_t* __restrict__ kh, bf16_t* __restrict__ vt) {
  __shared__ bf16_t As[4096];  // [128][32]
  __shared__ bf16_t Bs[4096];  // [128][32]
  const int tid = threadIdx.x;
  const int lane = tid & 63;
  const int w = tid >> 6;
  const int wm = w >> 1, wn = w & 1;
  const int m0 = blockIdx.y * 128;
  const int n0 = blockIdx.x * 128;

  f32x4 acc[4][4];
#pragma unroll
  for (int m = 0; m < 4; ++m)
#pragma unroll
    for (int n = 0; n < 4; ++n) acc[m][n] = (f32x4){0.f, 0.f, 0.f, 0.f};

  const int srow = tid >> 2;
  const int scol = (tid & 3) * 8;
  const int fr = lane & 15;
  const int g4 = lane >> 4;
  const int kg = g4 * 8;

  for (int k0 = 0; k0 < K; k0 += 32) {
#pragma unroll
    for (int p = 0; p < 2; ++p) {
      g2l16(A + (long long)(m0 + p * 64 + srow) * lda + (k0 + scol), As + p * 2048 + w * 512);
      g2l16(B + (long long)(n0 + p * 64 + srow) * ldb + (k0 + scol), Bs + p * 2048 + w * 512);
    }
    __syncthreads();
    bf16x8 fa[4], fb[4];
#pragma unroll
    for (int m = 0; m < 4; ++m)
      fa[m] = *(const bf16x8*)(As + (wm * 64 + m * 16 + fr) * 32 + kg);
#pragma unroll
    for (int n = 0; n < 4; ++n)
      fb[n] = *(const bf16x8*)(Bs + (wn * 64 + n * 16 + fr) * 32 + kg);
#pragma unroll
    for (int m = 0; m < 4; ++m)
#pragma unroll
      for (int n = 0; n < 4; ++n)
        acc[m][n] = __builtin_amdgcn_mfma_f32_16x16x32_bf16(fa[m], fb[n], acc[m][n], 0, 0, 0);
    __syncthreads();
  }

#pragma unroll
  for (int n = 0; n < 4; ++n) {
    const int col = n0 + wn * 64 + n * 16 + fr;
    const float bv = BIAS ? bias[col] : 0.0f;
    if (EPI == 1) {
      const int reg = col >> 9;
      const int h = (col >> 6) & 7;
      const int hd = col & 63;
#pragma unroll
      for (int m = 0; m < 4; ++m) {
        const int rb = m0 + wm * 64 + m * 16 + g4 * 4;
#pragma unroll
        for (int r = 0; r < 4; ++r) {
          const int row = rb + r;
          const int b = row >> 11, t = row & 2047;
          const long long bh = (long long)b * 8 + h;
          float v = acc[m][n][r] + bv;
          if (reg == 0) qh[(bh * 2048 + t) * 64 + hd] = (bf16_t)(v * 0.125f);
          else if (reg == 1) kh[(bh * 2048 + t) * 64 + hd] = (bf16_t)v;
          else vt[(bh * 64 + hd) * 2048 + t] = (bf16_t)v;
        }
      }
    } else {
#pragma unroll
      for (int m = 0; m < 4; ++m) {
        const long long rb = m0 + wm * 64 + m * 16 + g4 * 4;
#pragma unroll
        for (int r = 0; r < 4; ++r) {
          float v = (acc[m][n][r] + bv) * alpha;
          if (EPI == 2) v = gelu_f(v);
          C[(rb + r) * (long long)ldc + col] = (CT)v;
        }
      }
    }
  }
}

// ---------------- 64x128 GEMM (for small-N shapes; full-CU grids) ----------------
template <typename CT, bool BIAS>
__global__ __launch_bounds__(256, 4) void k_gemm64(
    const bf16_t* __restrict__ A, int lda, const bf16_t* __restrict__ B, int ldb,
    CT* __restrict__ C, int ldc, const float* __restrict__ bias, int K, float alpha) {
  __shared__ bf16_t As[64 * 32];
  __shared__ bf16_t Bs[128 * 32];
  const int tid = threadIdx.x;
  const int lane = tid & 63;
  const int w = tid >> 6;
  const int wm = w >> 1, wn = w & 1;
  const int m0 = blockIdx.y * 64;
  const int n0 = blockIdx.x * 128;

  f32x4 acc[2][4];
#pragma unroll
  for (int m = 0; m < 2; ++m)
#pragma unroll
    for (int n = 0; n < 4; ++n) acc[m][n] = (f32x4){0.f, 0.f, 0.f, 0.f};

  const int srow = tid >> 2;
  const int scol = (tid & 3) * 8;
  const int fr = lane & 15;
  const int g4 = lane >> 4;
  const int kg = g4 * 8;

  for (int k0 = 0; k0 < K; k0 += 32) {
    g2l16(A + (long long)(m0 + srow) * lda + (k0 + scol), As + tid * 8);
    g2l16(B + (long long)(n0 + srow) * ldb + (k0 + scol), Bs + tid * 8);
    g2l16(B + (long long)(n0 + 64 + srow) * ldb + (k0 + scol), Bs + 2048 + tid * 8);
    __syncthreads();
    bf16x8 fa[2], fb[4];
#pragma unroll
    for (int m = 0; m < 2; ++m)
      fa[m] = *(const bf16x8*)(As + (wm * 32 + m * 16 + fr) * 32 + kg);
#pragma unroll
    for (int n = 0; n < 4; ++n)
      fb[n] = *(const bf16x8*)(Bs + (wn * 64 + n * 16 + fr) * 32 + kg);
#pragma unroll
    for (int m = 0; m < 2; ++m)
#pragma unroll
      for (int n = 0; n < 4; ++n)
        acc[m][n] = __builtin_amdgcn_mfma_f32_16x16x32_bf16(fa[m], fb[n], acc[m][n], 0, 0, 0);
    __syncthreads();
  }

#pragma unroll
  for (int n = 0; n < 4; ++n) {
    const int col = n0 + wn * 64 + n * 16 + fr;
    const float bv = BIAS ? bias[col] : 0.0f;
#pragma unroll
    for (int m = 0; m < 2; ++m) {
      const long long rb = m0 + wm * 32 + m * 16 + g4 * 4;
#pragma unroll
      for (int r = 0; r < 4; ++r)
        C[(rb + r) * (long long)ldc + col] = (CT)((acc[m][n][r] + bv) * alpha);
    }
  }
}

// ---------------- 256x256 GEMM, BK=64, 8 waves, counted-vmcnt 2-phase pipeline ----------------
// Requires M%256==0, N%256==0, K%64==0. C = (A[M,K] @ B[N,K]^T) * alpha.
// LDS: buf{0,1} x { A-plane0, A-plane1, B-plane0, B-plane1 }, plane = [256 rows][32 k] bf16,
// rows XOR-swizzled by (row&3)<<4 (pre-swizzled global source, linear g2l dest).
template <typename CT>
__global__ __launch_bounds__(512, 2) void k_gemm256(
    const bf16_t* __restrict__ A, int lda, const bf16_t* __restrict__ B, int ldb,
    CT* __restrict__ C, int ldc, int K, float alpha) {
  __shared__ char lds[131072];
  const int tid = threadIdx.x;
  const int lane = tid & 63;
  const int w = tid >> 6;
  const int wm = w >> 2, wn = w & 3;
  const int fr = lane & 15;
  const int g4 = lane >> 4;

  // XCD-bijective block swizzle on the linear grid (nwg is a multiple of 8 for our shapes)
  int nwg = gridDim.x * gridDim.y;
  int lin = blockIdx.y * gridDim.x + blockIdx.x;
  if ((nwg & 7) == 0) lin = (lin & 7) * (nwg >> 3) + (lin >> 3);
  const int m0 = (lin / gridDim.x) * 256;
  const int n0 = (lin % gridDim.x) * 256;

  f32x4 acc[8][4];
#pragma unroll
  for (int m = 0; m < 8; ++m)
#pragma unroll
    for (int n = 0; n < 4; ++n) acc[m][n] = (f32x4){0.f, 0.f, 0.f, 0.f};

  const int sr = tid >> 2;           // staging row 0..127
  const int sc = (tid & 3) * 16;     // staging col-byte 0..48
  const int NT = K >> 6;

  // stage K-plane p of tile t into buf: A(2 loads) then B(2 loads) per thread
  auto stage = [&](int t, int p, int buf) {
    const long long kb = (long long)t * 128 + p * 64;  // byte offset along K
    char* ab = (char*)lds + buf * 65536 + p * 16384;
    char* bb = ab + 32768;
    const int sw = (sr & 3) << 4;  // (r&3) identical for r and r+128
    g2l16((const char*)A + (long long)(m0 + sr) * (lda * 2) + kb + (sc ^ sw), ab + tid * 16);
    g2l16((const char*)A + (long long)(m0 + 128 + sr) * (lda * 2) + kb + (sc ^ sw),
          ab + (tid + 512) * 16);
    g2l16((const char*)B + (long long)(n0 + sr) * (ldb * 2) + kb + (sc ^ sw), bb + tid * 16);
    g2l16((const char*)B + (long long)(n0 + 128 + sr) * (ldb * 2) + kb + (sc ^ sw),
          bb + (tid + 512) * 16);
  };

  // prologue: tile 0, both planes; publish plane 0 (keep plane 1 in flight)
  stage(0, 0, 0);
  stage(0, 1, 0);
  asm volatile("s_waitcnt vmcnt(4)" ::: "memory");
  __builtin_amdgcn_s_barrier();
  __builtin_amdgcn_sched_barrier(0);

  int cur = 0;
  for (int t = 0; t < NT; ++t) {
#pragma unroll
    for (int p = 0; p < 2; ++p) {
      const char* ab = (const char*)lds + cur * 65536 + p * 16384;
      const char* bb = ab + 32768;
      bf16x8 fa[8], fb[4];
#pragma unroll
      for (int m = 0; m < 8; ++m) {
        const int row = wm * 128 + m * 16 + fr;
        fa[m] = *(const bf16x8*)(ab + row * 64 + ((g4 * 16) ^ ((row & 3) << 4)));
      }
#pragma unroll
      for (int n = 0; n < 4; ++n) {
        const int row = wn * 64 + n * 16 + fr;
        fb[n] = *(const bf16x8*)(bb + row * 64 + ((g4 * 16) ^ ((row & 3) << 4)));
      }
      if (t + 1 < NT) stage(t + 1, p, cur ^ 1);
      // publish the plane needed by the NEXT phase; never drain in steady state
      if (t == NT - 1 && p == 0) {
        asm volatile("s_waitcnt vmcnt(0)" ::: "memory");
      } else {
        asm volatile("s_waitcnt vmcnt(4)" ::: "memory");
      }
      __builtin_amdgcn_s_barrier();
      __builtin_amdgcn_sched_barrier(0);
      __builtin_amdgcn_s_setprio(1);
#pragma unroll
      for (int m = 0; m < 8; ++m)
#pragma unroll
        for (int n = 0; n < 4; ++n)
          acc[m][n] = __builtin_amdgcn_mfma_f32_16x16x32_bf16(fa[m], fb[n], acc[m][n], 0, 0, 0);
      __builtin_amdgcn_s_setprio(0);
    }
    cur ^= 1;
  }

#pragma unroll
  for (int n = 0; n < 4; ++n) {
    const int col = n0 + wn * 64 + n * 16 + fr;
#pragma unroll
    for (int m = 0; m < 8; ++m) {
      const long long rb = m0 + wm * 128 + m * 16 + g4 * 4;
#pragma unroll
      for (int r = 0; r < 4; ++r)
        C[(rb + r) * (long long)ldc + col] = (CT)(acc[m][n][r] * alpha);
    }
  }
}

// ---------------- fused flash attention ----------------
__global__ __launch_bounds__(256, 2) void k_flash(
    const bf16_t* __restrict__ qh, const bf16_t* __restrict__ kh,
    const bf16_t* __restrict__ vt, bf16_t* __restrict__ out) {
  __shared__ bf16_t Ks[128 * 64];
  __shared__ bf16_t Vs[64 * 128];
  __shared__ bf16_t Ps[4 * 32 * 128];
  const int tid = threadIdx.x;
  const int lane = tid & 63;
  const int w = tid >> 6;
  const int bh = blockIdx.y;
  const int q0 = blockIdx.x * 128;
  const int fr = lane & 15;
  const int g4 = lane >> 4;
  const int kg = g4 * 8;

  bf16x8 qf[2][2];
  {
    const bf16_t* qb = qh + ((long long)bh * 2048 + q0 + w * 32) * 64;
#pragma unroll
    for (int m = 0; m < 2; ++m)
#pragma unroll
      for (int ks = 0; ks < 2; ++ks)
        qf[m][ks] = *(const bf16x8*)(qb + (m * 16 + fr) * 64 + ks * 32 + kg);
  }

  f32x4 oacc[2][4];
#pragma unroll
  for (int m = 0; m < 2; ++m)
#pragma unroll
    for (int n = 0; n < 4; ++n) oacc[m][n] = (f32x4){0.f, 0.f, 0.f, 0.f};
  float mi[8], li[8];
#pragma unroll
  for (int j = 0; j < 8; ++j) { mi[j] = -1e30f; li[j] = 0.f; }

  char* PsW = (char*)(Ps + w * 32 * 128);
  const bf16_t* kbase = kh + (long long)bh * 2048 * 64;
  const bf16_t* vbase = vt + (long long)bh * 64 * 2048;

  for (int kt = 0; kt < 16; ++kt) {
#pragma unroll
    for (int i = 0; i < 4; ++i) {
      int row = (w * 4 + i) * 8 + (lane >> 3);
      int c = lane & 7;
      g2l16(kbase + ((long long)(kt * 128 + row)) * 64 + (c ^ (row & 7)) * 8,
            Ks + (w * 4 + i) * 512);
    }
#pragma unroll
    for (int i = 0; i < 4; ++i) {
      int d = w * 16 + i * 4 + (lane >> 4);
      int c = lane & 15;
      g2l16(vbase + (long long)d * 2048 + kt * 128 + ((c ^ (d & 7)) * 8),
            Vs + (w * 16 + i * 4) * 128);
    }
    __syncthreads();

    f32x4 s[2][8];
#pragma unroll
    for (int m = 0; m < 2; ++m)
#pragma unroll
      for (int n = 0; n < 8; ++n) s[m][n] = (f32x4){0.f, 0.f, 0.f, 0.f};
#pragma unroll
    for (int ks = 0; ks < 2; ++ks) {
#pragma unroll
      for (int n = 0; n < 8; ++n) {
        int row = n * 16 + fr;
        bf16x8 kf = *(const bf16x8*)((const char*)Ks + row * 128 +
                                     ((ks * 64 + kg * 2) ^ ((row & 7) << 4)));
#pragma unroll
        for (int m = 0; m < 2; ++m)
          s[m][n] = __builtin_amdgcn_mfma_f32_16x16x32_bf16(qf[m][ks], kf, s[m][n], 0, 0, 0);
      }
    }

#pragma unroll
    for (int m = 0; m < 2; ++m) {
#pragma unroll
      for (int r = 0; r < 4; ++r) {
        float pm = -1e30f;
#pragma unroll
        for (int n = 0; n < 8; ++n) pm = fmaxf(pm, s[m][n][r]);
        pm = fmaxf(pm, __shfl_xor(pm, 1));
        pm = fmaxf(pm, __shfl_xor(pm, 2));
        pm = fmaxf(pm, __shfl_xor(pm, 4));
        pm = fmaxf(pm, __shfl_xor(pm, 8));
        const int ri = m * 4 + r;
        const float mnew = fmaxf(mi[ri], pm);
        const float alpha = __expf(mi[ri] - mnew);
        mi[ri] = mnew;
        const int lr = m * 16 + g4 * 4 + r;
        const int sw = (lr & 7) << 4;
        float rs = 0.f;
#pragma unroll
        for (int n = 0; n < 8; ++n) {
          float p = __expf(s[m][n][r] - mnew);
          rs += p;
          *(bf16_t*)(PsW + lr * 256 + (((n * 16 + fr) * 2) ^ sw)) = (bf16_t)p;
        }
        rs += __shfl_xor(rs, 1);
        rs += __shfl_xor(rs, 2);
        rs += __shfl_xor(rs, 4);
        rs += __shfl_xor(rs, 8);
        li[ri] = li[ri] * alpha + rs;
#pragma unroll
        for (int n = 0; n < 4; ++n) oacc[m][n][r] *= alpha;
      }
    }

#pragma unroll
    for (int ks = 0; ks < 4; ++ks) {
      bf16x8 pa[2];
#pragma unroll
      for (int m = 0; m < 2; ++m) {
        int row = m * 16 + fr;
        pa[m] = *(const bf16x8*)(PsW + row * 256 + ((ks * 64 + kg * 2) ^ ((row & 7) << 4)));
      }
#pragma unroll
      for (int n = 0; n < 4; ++n) {
        int d = n * 16 + fr;
        bf16x8 vf = *(const bf16x8*)((const char*)Vs + d * 256 +
                                     ((ks * 64 + kg * 2) ^ ((d & 7) << 4)));
#pragma unroll
        for (int m = 0; m < 2; ++m)
          oacc[m][n] = __builtin_amdgcn_mfma_f32_16x16x32_bf16(pa[m], vf, oacc[m][n], 0, 0, 0);
      }
    }
    __syncthreads();
  }

  const int b = bh >> 3, h = bh & 7;
  bf16_t* ob = out + ((long long)b * 2048 + q0 + w * 32) * 512 + h * 64;
#pragma unroll
  for (int m = 0; m < 2; ++m)
#pragma unroll
    for (int r = 0; r < 4; ++r) {
      float inv = 1.0f / li[m * 4 + r];
#pragma unroll
      for (int n = 0; n < 4; ++n)
        ob[(m * 16 + g4 * 4 + r) * 512 + n * 16 + fr] = (bf16_t)(oacc[m][n][r] * inv);
    }
}

// ---------------- LN(xin + delta) * s + b -> xout (f32) + xbf (bf16), D=512 ----------------
__global__ void k_ln(const float* __restrict__ xin, const float* __restrict__ delta,
                     const float* __restrict__ s, const float* __restrict__ b,
                     float* __restrict__ xout, bf16_t* __restrict__ xbf) {
  __shared__ float red[8];
  const int r = blockIdx.x;
  const int tid = threadIdx.x;
  const int d = tid * 2;
  const int lane = tid & 63, w = tid >> 6;
  float2 xi = *(const float2*)(xin + (long)r * 512 + d);
  float2 de = *(const float2*)(delta + (long)r * 512 + d);
  float y0 = xi.x + de.x, y1 = xi.y + de.y;
  float sum = y0 + y1, ss = y0 * y0 + y1 * y1;
#pragma unroll
  for (int o = 32; o > 0; o >>= 1) { sum += __shfl_xor(sum, o); ss += __shfl_xor(ss, o); }
  if (lane == 0) { red[w] = sum; red[4 + w] = ss; }
  __syncthreads();
  sum = red[0] + red[1] + red[2] + red[3];
  ss = red[4] + red[5] + red[6] + red[7];
  const float mean = sum * (1.0f / 512.0f);
  const float var = ss * (1.0f / 512.0f) - mean * mean;
  const float rstd = rsqrtf(var + 1e-5f);
  float o0 = (y0 - mean) * rstd * s[d] + b[d];
  float o1 = (y1 - mean) * rstd * s[d + 1] + b[d + 1];
  *(float2*)(xout + (long)r * 512 + d) = make_float2(o0, o1);
  bf16x2 ob = {(bf16_t)o0, (bf16_t)o1};
  *(bf16x2*)(xbf + (long)r * 512 + d) = ob;
}

// ---------------- top-4 over bf16 score row + f32 salience ----------------
DEVI bool tk_better(float av, int ai, float bv, int bi) {
  return (av > bv) || (av == bv && ai < bi);
}
DEVI void tk_insert(float* v, int* ix, float nv, int ni) {
  if (!tk_better(nv, ni, v[3], ix[3])) return;
  v[3] = nv; ix[3] = ni;
#pragma unroll
  for (int j = 3; j > 0; --j) {
    if (tk_better(v[j], ix[j], v[j - 1], ix[j - 1])) {
      float tv_ = v[j]; v[j] = v[j - 1]; v[j - 1] = tv_;
      int ti_ = ix[j]; ix[j] = ix[j - 1]; ix[j - 1] = ti_;
    }
  }
}
__global__ void k_topk(const bf16_t* __restrict__ sc, const float* __restrict__ sal,
                       int ncol, float* __restrict__ tv, int* __restrict__ ti) {
  const int r = blockIdx.x * 4 + (threadIdx.x >> 6);
  const int lane = threadIdx.x & 63;
  float v[4] = {-1e30f, -1e30f, -1e30f, -1e30f};
  int ix[4] = {0x7fffffff, 0x7fffffff, 0x7fffffff, 0x7fffffff};
  const bf16_t* row = sc + (long)r * ncol;
  for (int c0 = lane * 8; c0 < ncol; c0 += 512) {
    bf16x8 sv = *(const bf16x8*)(row + c0);
    float4 s0 = *(const float4*)(sal + c0);
    float4 s1 = *(const float4*)(sal + c0 + 4);
    tk_insert(v, ix, (float)sv[0] + s0.x, c0 + 0);
    tk_insert(v, ix, (float)sv[1] + s0.y, c0 + 1);
    tk_insert(v, ix, (float)sv[2] + s0.z, c0 + 2);
    tk_insert(v, ix, (float)sv[3] + s0.w, c0 + 3);
    tk_insert(v, ix, (float)sv[4] + s1.x, c0 + 4);
    tk_insert(v, ix, (float)sv[5] + s1.y, c0 + 5);
    tk_insert(v, ix, (float)sv[6] + s1.z, c0 + 6);
    tk_insert(v, ix, (float)sv[7] + s1.w, c0 + 7);
  }
#pragma unroll
  for (int dd = 1; dd < 64; dd <<= 1) {
    float ov[4]; int oi[4];
#pragma unroll
    for (int j = 0; j < 4; ++j) { ov[j] = __shfl_xor(v[j], dd); oi[j] = __shfl_xor(ix[j], dd); }
#pragma unroll
    for (int j = 0; j < 4; ++j) tk_insert(v, ix, ov[j], oi[j]);
  }
  if (lane == 0) {
#pragma unroll
    for (int j = 0; j < 4; ++j) { tv[(long)r * 4 + j] = v[j]; ti[(long)r * 4 + j] = ix[j]; }
  }
}

// ---------------- gather V by top-4, softmax weights, avg over 3 levels ----------------
__global__ void k_read(const float* __restrict__ tv, const int* __restrict__ ti,
                       const float* __restrict__ V0, const float* __restrict__ V1,
                       const float* __restrict__ V2, bf16_t* __restrict__ readb) {
  const int r = blockIdx.x;
  const int d = threadIdx.x * 2;
  float a0 = 0.f, a1 = 0.f;
  const float* Vs[3] = {V0, V1, V2};
#pragma unroll
  for (int lev = 0; lev < 3; ++lev) {
    const float* tvr = tv + ((long)lev * 4096 + r) * 4;
    const int* tir = ti + ((long)lev * 4096 + r) * 4;
    float t0 = tvr[0], t1 = tvr[1], t2 = tvr[2], t3 = tvr[3];
    float m = fmaxf(fmaxf(t0, t1), fmaxf(t2, t3));
    float e0 = __expf(t0 - m), e1 = __expf(t1 - m), e2 = __expf(t2 - m), e3 = __expf(t3 - m);
    float inv = 1.0f / (e0 + e1 + e2 + e3);
    float w4[4] = {e0 * inv, e1 * inv, e2 * inv, e3 * inv};
#pragma unroll
    for (int k = 0; k < 4; ++k) {
      const float* vr = Vs[lev] + (long)tir[k] * 512;
      a0 += w4[k] * vr[d];
      a1 += w4[k] * vr[d + 1];
    }
  }
  bf16x2 o = {(bf16_t)(a0 * (1.0f / 3.0f)), (bf16_t)(a1 * (1.0f / 3.0f))};
  *(bf16x2*)(readb + (long)r * 512 + d) = o;
}

// ---------------- host ----------------
extern "C" void kernel_launch(void* const* d_in, const int* in_sizes, int n_in,
                              void* d_out, int out_size, void* d_ws, size_t ws_size,
                              hipStream_t stream) {
  (void)in_sizes; (void)n_in; (void)out_size; (void)ws_size;
  const int* ids = (const int*)d_in[0];
  const float* tok = (const float*)d_in[1];
  const float* pos = (const float*)d_in[2];
  const float* Wqkv = (const float*)d_in[3];
  const float* bqkv = (const float*)d_in[4];
  const float* Wo = (const float*)d_in[5];
  const float* bo = (const float*)d_in[6];
  const float* ln1s = (const float*)d_in[7];
  const float* ln1b = (const float*)d_in[8];
  const float* W1 = (const float*)d_in[9];
  const float* b1 = (const float*)d_in[10];
  const float* W2 = (const float*)d_in[11];
  const float* b2 = (const float*)d_in[12];
  const float* ln2s = (const float*)d_in[13];
  const float* ln2b = (const float*)d_in[14];
  const float* Wq = (const float*)d_in[15];
  const float* bq = (const float*)d_in[16];
  const float* Wrp = (const float*)d_in[17];
  const float* brp = (const float*)d_in[18];
  const float* lnos = (const float*)d_in[19];
  const float* lnob = (const float*)d_in[20];
  const float* K0 = (const float*)d_in[21];
  const float* V0 = (const float*)d_in[22];
  const float* s0 = (const float*)d_in[23];
  const float* K1 = (const float*)d_in[24];
  const float* V1 = (const float*)d_in[25];
  const float* s1 = (const float*)d_in[26];
  const float* K2 = (const float*)d_in[27];
  const float* V2 = (const float*)d_in[28];
  const float* s2 = (const float*)d_in[29];

  char* wp = (char*)d_ws;
  auto walloc = [&](size_t bytes) -> char* {
    char* p = wp; wp += (bytes + 255) & ~(size_t)255; return p;
  };
  char* op = (char*)d_out;
  auto oalloc = [&](size_t bytes) -> char* {
    char* p = op; op += (bytes + 255) & ~(size_t)255; return p;
  };

  // transients in d_out (all reads complete before lm_head overwrites d_out)
  bf16_t* Wqkvb = (bf16_t*)oalloc(3145728ULL * 2);
  bf16_t* Wob   = (bf16_t*)oalloc(1048576ULL * 2);
  bf16_t* W1b   = (bf16_t*)oalloc(4194304ULL * 2);
  bf16_t* W2b   = (bf16_t*)oalloc(4194304ULL * 2);
  bf16_t* Wqb   = (bf16_t*)oalloc(262144ULL * 2);
  bf16_t* Wrpb  = (bf16_t*)oalloc(262144ULL * 2);
  bf16_t* Kb    = (bf16_t*)oalloc(28672ULL * 512 * 2);
  bf16_t* hb    = (bf16_t*)oalloc(4096ULL * 2048 * 2);
  bf16_t* scb   = (bf16_t*)oalloc(4096ULL * 16384 * 2);

  // survivors in d_ws
  bf16_t* tokb = (bf16_t*)walloc(16384000ULL * 2);
  float*  x    = (float*)walloc(4096ULL * 512 * 4);
  bf16_t* xb   = (bf16_t*)walloc(4096ULL * 512 * 2);
  bf16_t* qh   = (bf16_t*)walloc(2097152ULL * 2);
  bf16_t* kh   = (bf16_t*)walloc(2097152ULL * 2);
  bf16_t* vt   = (bf16_t*)walloc(2097152ULL * 2);
  bf16_t* attob = (bf16_t*)walloc(4096ULL * 512 * 2);
  float*  delta = (float*)walloc(4096ULL * 512 * 4);
  bf16_t* qmb  = (bf16_t*)walloc(4096ULL * 512 * 2);
  bf16_t* readb = (bf16_t*)walloc(4096ULL * 512 * 2);
  float*  tval = (float*)walloc(3ULL * 4096 * 4 * 4);
  int*    tidx = (int*)walloc(3ULL * 4096 * 4 * 4);
  bf16_t* xfb  = (bf16_t*)walloc(4096ULL * 512 * 2);

  auto f2b = [&](const float* in, bf16_t* o, long n) {
    k_f2b<<<1024, 256, 0, stream>>>(in, o, n / 4);
  };
  f2b(tok, tokb, 16384000L);
  f2b(Wqkv, Wqkvb, 3145728L);
  f2b(Wo, Wob, 1048576L);
  f2b(W1, W1b, 4194304L);
  f2b(W2, W2b, 4194304L);
  f2b(Wq, Wqb, 262144L);
  f2b(Wrp, Wrpb, 262144L);
  f2b(K0, Kb, 8388608L);
  f2b(K1, Kb + 8388608L, 4194304L);
  f2b(K2, Kb + 12582912L, 2097152L);

  k_embed<<<4096, 256, 0, stream>>>(ids, tok, pos, x, xb);

  for (int i = 0; i < 4; ++i) {
    // QKV GEMM with fused split epilogue
    k_gemm_bt<bf16_t, true, 1><<<dim3(12, 32), 256, 0, stream>>>(
        xb, 512, Wqkvb + (long long)i * 786432, 512, (bf16_t*)nullptr, 0,
        bqkv + i * 1536, 512, 1.0f, qh, kh, vt);
    k_flash<<<dim3(16, 16), 256, 0, stream>>>(qh, kh, vt, attob);
    k_gemm64<float, true><<<dim3(4, 64), 256, 0, stream>>>(
        attob, 512, Wob + (long long)i * 262144, 512, delta, 512, bo + i * 512, 512, 1.0f);
    k_ln<<<4096, 256, 0, stream>>>(x, delta, ln1s + i * 512, ln1b + i * 512, x, xb);
    // W1 GEMM with fused GELU
    k_gemm_bt<bf16_t, true, 2><<<dim3(16, 32), 256, 0, stream>>>(
        xb, 512, W1b + (long long)i * 1048576, 512, hb, 2048,
        b1 + i * 2048, 512, 1.0f, nullptr, nullptr, nullptr);
    k_gemm64<float, true><<<dim3(4, 64), 256, 0, stream>>>(
        hb, 2048, W2b + (long long)i * 1048576, 2048, delta, 512, b2 + i * 512, 2048, 1.0f);
    k_ln<<<4096, 256, 0, stream>>>(x, delta, ln2s + i * 512, ln2b + i * 512, x, xb);
  }

  // memory path: qm = (x@Wq^T + bq)/sqrt(512) in bf16
  k_gemm64<bf16_t, true><<<dim3(4, 64), 256, 0, stream>>>(
      xb, 512, Wqb, 512, qmb, 512, bq, 512, 0.044194173824159216f);
  const float* sal[3] = {s0, s1, s2};
  const int slots[3] = {16384, 8192, 4096};
  long koff = 0;
  for (int lev = 0; lev < 3; ++lev) {
    k_gemm256<bf16_t><<<dim3(slots[lev] / 256, 16), 512, 0, stream>>>(
        qmb, 512, Kb + koff * 512, 512, scb, slots[lev], 512, 1.0f);
    k_topk<<<1024, 256, 0, stream>>>(scb, sal[lev], slots[lev],
                                     tval + (long)lev * 16384, tidx + (long)lev * 16384);
    koff += slots[lev];
  }
  k_read<<<4096, 256, 0, stream>>>(tval, tidx, V0, V1, V2, readb);
  k_gemm64<float, true><<<dim3(4, 64), 256, 0, stream>>>(
      readb, 512, Wrpb, 512, delta, 512, brp, 512, 1.0f);
  k_ln<<<4096, 256, 0, stream>>>(x, delta, lnos, lnob, x, xfb);
  // logits = x @ tok_embed^T  (f32, overwrites all d_out scratch)
  k_gemm256<float><<<dim3(125, 16), 512, 0, stream>>>(
      xfb, 512, tokb, 512, (float*)d_out, 32000, 512, 1.0f);
}